// Round 3
// baseline (122.883 us; speedup 1.0000x reference)
//
#include <hip/hip_runtime.h>
#include <math.h>

#define NB 131072
#define NM 32
#define EC 2.7182818284590452f
#define TS 0.17677669529663687f   // 1/sqrt(32)
#define L2E 1.4426950408889634f
#define LN2F 0.6931471805599453f

// ws layout (floats):
//   [2048, 2048+8192): per-block partial column mins (256 blocks x 32 cols)
// (Gsym + mode_min slots no longer needed: pair loop reads Gamma[i*32+j]
//  directly since i<j always, and the final min reduce moved into k_main.)

#if __has_builtin(__builtin_amdgcn_exp2f)
__device__ __forceinline__ float fexp2(float x) { return __builtin_amdgcn_exp2f(x); }
#else
__device__ __forceinline__ float fexp2(float x) { return exp2f(x); }
#endif
#if __has_builtin(__builtin_amdgcn_logf)
__device__ __forceinline__ float flog2(float x) { return __builtin_amdgcn_logf(x); }
#else
__device__ __forceinline__ float flog2(float x) { return __log2f(x); }
#endif
#if __has_builtin(__builtin_amdgcn_rcpf)
__device__ __forceinline__ float frcp(float x) { return __builtin_amdgcn_rcpf(x); }
#else
__device__ __forceinline__ float frcp(float x) { return 1.0f / x; }
#endif

// ---------------- Kernel A: per-block partial column minima ----------------
__global__ __launch_bounds__(256) void k_min(const float* __restrict__ phi,
                                             float* __restrict__ ws) {
    __shared__ float sm[1024];
    const int tid = threadIdx.x;
    const int g = blockIdx.x * 256 + tid;
    const float4* __restrict__ p4 = (const float4*)phi;
    float4 m = p4[g];
    #pragma unroll
    for (int k = 1; k < 16; ++k) {
        float4 v = p4[g + k * 65536];
        m.x = fminf(m.x, v.x); m.y = fminf(m.y, v.y);
        m.z = fminf(m.z, v.z); m.w = fminf(m.w, v.w);
    }
    sm[tid * 4 + 0] = m.x; sm[tid * 4 + 1] = m.y;
    sm[tid * 4 + 2] = m.z; sm[tid * 4 + 3] = m.w;
    __syncthreads();
    #pragma unroll
    for (int s = 128; s >= 8; s >>= 1) {
        if (tid < s) {
            sm[tid * 4 + 0] = fminf(sm[tid * 4 + 0], sm[(tid + s) * 4 + 0]);
            sm[tid * 4 + 1] = fminf(sm[tid * 4 + 1], sm[(tid + s) * 4 + 1]);
            sm[tid * 4 + 2] = fminf(sm[tid * 4 + 2], sm[(tid + s) * 4 + 2]);
            sm[tid * 4 + 3] = fminf(sm[tid * 4 + 3], sm[(tid + s) * 4 + 3]);
        }
        __syncthreads();
    }
    if (tid < 8) {
        #pragma unroll
        for (int s2 = 0; s2 < 4; ++s2)
            ws[2048 + blockIdx.x * 32 + tid * 4 + s2] = sm[tid * 4 + s2];
    }
}

// ---------------- Kernel C: main (row-per-thread) --------------------------
// 512 blocks x 256 threads, one row per thread. FULLY UNROLLED: every array
// index is compile-time-constant, so L[32]/acc[32]/xs[32] live purely in
// registers. Prologue does the final column-min reduce in-block (8 KB of
// partials, L2-resident, overlapped with the independent phi global loads)
// — the old k_prep dispatch is deleted. Pair loop reads Gamma[i*32+j]
// directly (i<j always => Gsym[i][j]==Gamma[i][j]); g's are wave-uniform
// s_loads with imm offsets <= 4092B. __launch_bounds__(256,4) caps VGPR at
// 128 -> 4 waves/SIMD (was 2) for trans-pipe/s_load latency hiding; live
// state ~100 VGPR so no spill expected.
__global__ __launch_bounds__(256, 4) void k_main(const float* __restrict__ phi,
                                                 const float* __restrict__ w,
                                                 const float* __restrict__ Gamma,
                                                 const float* __restrict__ ws,
                                                 float* __restrict__ out) {
    __shared__ float sm[256];
    __shared__ float smin[32];
    const int tid = threadIdx.x;
    const size_t row = (size_t)blockIdx.x * 256 + tid;
    const float* __restrict__ pr = phi + row * NM;

    // ---- block-local final min reduce: mme[c] = min_b partials[b][c] - e
    {
        const int c = tid & 31, h = tid >> 5;    // 8 groups of 32 partial-rows
        float mpart = INFINITY;
        #pragma unroll
        for (int b = 0; b < 32; ++b)
            mpart = fminf(mpart, ws[2048 + (h * 32 + b) * 32 + c]);
        sm[tid] = mpart;
        __syncthreads();
        if (tid < 32) {
            float mm = sm[tid];
            #pragma unroll
            for (int g2 = 1; g2 < 8; ++g2) mm = fminf(mm, sm[g2 * 32 + tid]);
            smin[tid] = mm - EC;
        }
        __syncthreads();
    }

    float L[32];
    float acc[32];
    // load + clamp + log2; seed acc with the diagonal term (1+w_i)*phic_i
    #pragma unroll
    for (int k = 0; k < 8; ++k) {
        float4 v = ((const float4*)pr)[k];
        // phic = max(phi - mode_min + e, e) = max(phi - (mode_min - e), e)
        float p0 = fmaxf(v.x - smin[4 * k + 0], EC);
        float p1 = fmaxf(v.y - smin[4 * k + 1], EC);
        float p2 = fmaxf(v.z - smin[4 * k + 2], EC);
        float p3 = fmaxf(v.w - smin[4 * k + 3], EC);
        L[4 * k + 0] = flog2(p0); L[4 * k + 1] = flog2(p1);
        L[4 * k + 2] = flog2(p2); L[4 * k + 3] = flog2(p3);
        // (1+w)*p = fmaf(w, p, p)
        acc[4 * k + 0] = fmaf(w[4 * k + 0], p0, p0);
        acc[4 * k + 1] = fmaf(w[4 * k + 1], p1, p1);
        acc[4 * k + 2] = fmaf(w[4 * k + 2], p2, p2);
        acc[4 * k + 3] = fmaf(w[4 * k + 3], p3, p3);
    }

    // upper-triangle pairs, all indices static; g straight from Gamma (i<j)
    #pragma unroll
    for (int i = 0; i < 31; ++i) {
        #pragma unroll
        for (int j = i + 1; j < 32; ++j) {
            const float g = Gamma[i * 32 + j];   // uniform s_load, imm offset
            const float d = L[i] - L[j];
            acc[i] += fexp2(fmaf(g, d, L[j]));   // phic_i^g * phic_j^(1-g)
            acc[j] += fexp2(fmaf(g, -d, L[i]));  // phic_j^g * phic_i^(1-g)
        }
    }

    float xs[32];
    #pragma unroll
    for (int i = 0; i < 32; ++i) xs[i] = -TS * acc[i];
    float m = xs[0];
    #pragma unroll
    for (int i = 1; i < 32; ++i) m = fmaxf(m, xs[i]);
    float p[32];
    float s = 0.f;
    #pragma unroll
    for (int i = 0; i < 32; ++i) { p[i] = fexp2((xs[i] - m) * L2E); s += p[i]; }
    const float inv = frcp(s);
    const float lns = flog2(s) * LN2F;   // ln(s)

    float* __restrict__ oa = out + row * NM;
    float* __restrict__ ol = out + (size_t)NB * NM + row * NM;
    #pragma unroll
    for (int k = 0; k < 8; ++k) {
        float4 a4 = { p[4 * k + 0] * inv, p[4 * k + 1] * inv,
                      p[4 * k + 2] * inv, p[4 * k + 3] * inv };
        float4 l4 = { (xs[4 * k + 0] - m) - lns, (xs[4 * k + 1] - m) - lns,
                      (xs[4 * k + 2] - m) - lns, (xs[4 * k + 3] - m) - lns };
        ((float4*)oa)[k] = a4;
        ((float4*)ol)[k] = l4;
    }
}

extern "C" void kernel_launch(void* const* d_in, const int* in_sizes, int n_in,
                              void* d_out, int out_size, void* d_ws, size_t ws_size,
                              hipStream_t stream) {
    (void)in_sizes; (void)n_in; (void)out_size; (void)ws_size;
    const float* phi   = (const float*)d_in[0];
    const float* Gamma = (const float*)d_in[1];
    const float* w     = (const float*)d_in[2];
    float* out = (float*)d_out;
    float* wsf = (float*)d_ws;

    k_min<<<256, 256, 0, stream>>>(phi, wsf);
    k_main<<<512, 256, 0, stream>>>(phi, w, Gamma, wsf, out);
}

// Round 4
// 102.540 us; speedup vs baseline: 1.1984x; 1.1984x over previous
//
#include <hip/hip_runtime.h>
#include <math.h>

#define NB 131072
#define NM 32
#define EC 2.7182818284590452f
#define TS 0.17677669529663687f   // 1/sqrt(32)
#define L2E 1.4426950408889634f
#define LN2F 0.6931471805599453f

// ws layout (floats):
//   [2048, 2048+8192): per-block partial column mins (256 blocks x 32 cols)

#if __has_builtin(__builtin_amdgcn_exp2f)
__device__ __forceinline__ float fexp2(float x) { return __builtin_amdgcn_exp2f(x); }
#else
__device__ __forceinline__ float fexp2(float x) { return exp2f(x); }
#endif
#if __has_builtin(__builtin_amdgcn_logf)
__device__ __forceinline__ float flog2(float x) { return __builtin_amdgcn_logf(x); }
#else
__device__ __forceinline__ float flog2(float x) { return __log2f(x); }
#endif
#if __has_builtin(__builtin_amdgcn_rcpf)
__device__ __forceinline__ float frcp(float x) { return __builtin_amdgcn_rcpf(x); }
#else
__device__ __forceinline__ float frcp(float x) { return 1.0f / x; }
#endif

// ---------------- Kernel A: per-block partial column minima ----------------
__global__ __launch_bounds__(256) void k_min(const float* __restrict__ phi,
                                             float* __restrict__ ws) {
    __shared__ float sm[1024];
    const int tid = threadIdx.x;
    const int g = blockIdx.x * 256 + tid;
    const float4* __restrict__ p4 = (const float4*)phi;
    float4 m = p4[g];
    #pragma unroll
    for (int k = 1; k < 16; ++k) {
        float4 v = p4[g + k * 65536];
        m.x = fminf(m.x, v.x); m.y = fminf(m.y, v.y);
        m.z = fminf(m.z, v.z); m.w = fminf(m.w, v.w);
    }
    sm[tid * 4 + 0] = m.x; sm[tid * 4 + 1] = m.y;
    sm[tid * 4 + 2] = m.z; sm[tid * 4 + 3] = m.w;
    __syncthreads();
    #pragma unroll
    for (int s = 128; s >= 8; s >>= 1) {
        if (tid < s) {
            sm[tid * 4 + 0] = fminf(sm[tid * 4 + 0], sm[(tid + s) * 4 + 0]);
            sm[tid * 4 + 1] = fminf(sm[tid * 4 + 1], sm[(tid + s) * 4 + 1]);
            sm[tid * 4 + 2] = fminf(sm[tid * 4 + 2], sm[(tid + s) * 4 + 2]);
            sm[tid * 4 + 3] = fminf(sm[tid * 4 + 3], sm[(tid + s) * 4 + 3]);
        }
        __syncthreads();
    }
    if (tid < 8) {
        #pragma unroll
        for (int s2 = 0; s2 < 4; ++s2)
            ws[2048 + blockIdx.x * 32 + tid * 4 + s2] = sm[tid * 4 + s2];
    }
}

// ---------------- Kernel C: main (row-per-thread) --------------------------
// 512 blocks x 256 threads, one row per thread. FULLY UNROLLED: every array
// index is compile-time-constant, so L[32]/acc[32]/xs[32] live purely in
// registers. Prologue does the final column-min reduce in-block (8 KB of
// partials, L2-resident, overlapped with the independent phi global loads).
// Pair loop reads Gamma[i*32+j] directly (i<j => Gsym[i][j]==Gamma[i][j]);
// g's are wave-uniform s_loads with imm offsets.
// __launch_bounds__(256,2): the R3 experiment proved (256,4) forces the
// allocator to 64 VGPR and spills the whole register state to scratch
// (VGPR_Count=64, FETCH 41MB, k_main 57->63us). (256,2) is the known
// spill-free codegen (R2: k_main < 44us). Do not tighten without disasm
// evidence of headroom.
__global__ __launch_bounds__(256, 2) void k_main(const float* __restrict__ phi,
                                                 const float* __restrict__ w,
                                                 const float* __restrict__ Gamma,
                                                 const float* __restrict__ ws,
                                                 float* __restrict__ out) {
    __shared__ float sm[256];
    __shared__ float smin[32];
    const int tid = threadIdx.x;
    const size_t row = (size_t)blockIdx.x * 256 + tid;
    const float* __restrict__ pr = phi + row * NM;

    // ---- block-local final min reduce: smin[c] = min_b partials[b][c] - e
    {
        const int c = tid & 31, h = tid >> 5;    // 8 groups of 32 partial-rows
        float mpart = INFINITY;
        #pragma unroll
        for (int b = 0; b < 32; ++b)
            mpart = fminf(mpart, ws[2048 + (h * 32 + b) * 32 + c]);
        sm[tid] = mpart;
        __syncthreads();
        if (tid < 32) {
            float mm = sm[tid];
            #pragma unroll
            for (int g2 = 1; g2 < 8; ++g2) mm = fminf(mm, sm[g2 * 32 + tid]);
            smin[tid] = mm - EC;
        }
        __syncthreads();
    }

    float L[32];
    float acc[32];
    // load + clamp + log2; seed acc with the diagonal term (1+w_i)*phic_i
    #pragma unroll
    for (int k = 0; k < 8; ++k) {
        float4 v = ((const float4*)pr)[k];
        // phic = max(phi - mode_min + e, e) = max(phi - (mode_min - e), e)
        float p0 = fmaxf(v.x - smin[4 * k + 0], EC);
        float p1 = fmaxf(v.y - smin[4 * k + 1], EC);
        float p2 = fmaxf(v.z - smin[4 * k + 2], EC);
        float p3 = fmaxf(v.w - smin[4 * k + 3], EC);
        L[4 * k + 0] = flog2(p0); L[4 * k + 1] = flog2(p1);
        L[4 * k + 2] = flog2(p2); L[4 * k + 3] = flog2(p3);
        // (1+w)*p = fmaf(w, p, p)
        acc[4 * k + 0] = fmaf(w[4 * k + 0], p0, p0);
        acc[4 * k + 1] = fmaf(w[4 * k + 1], p1, p1);
        acc[4 * k + 2] = fmaf(w[4 * k + 2], p2, p2);
        acc[4 * k + 3] = fmaf(w[4 * k + 3], p3, p3);
    }

    // upper-triangle pairs, all indices static; g straight from Gamma (i<j)
    #pragma unroll
    for (int i = 0; i < 31; ++i) {
        #pragma unroll
        for (int j = i + 1; j < 32; ++j) {
            const float g = Gamma[i * 32 + j];   // uniform s_load, imm offset
            const float d = L[i] - L[j];
            acc[i] += fexp2(fmaf(g, d, L[j]));   // phic_i^g * phic_j^(1-g)
            acc[j] += fexp2(fmaf(g, -d, L[i]));  // phic_j^g * phic_i^(1-g)
        }
    }

    float xs[32];
    #pragma unroll
    for (int i = 0; i < 32; ++i) xs[i] = -TS * acc[i];
    float m = xs[0];
    #pragma unroll
    for (int i = 1; i < 32; ++i) m = fmaxf(m, xs[i]);
    float p[32];
    float s = 0.f;
    #pragma unroll
    for (int i = 0; i < 32; ++i) { p[i] = fexp2((xs[i] - m) * L2E); s += p[i]; }
    const float inv = frcp(s);
    const float lns = flog2(s) * LN2F;   // ln(s)

    float* __restrict__ oa = out + row * NM;
    float* __restrict__ ol = out + (size_t)NB * NM + row * NM;
    #pragma unroll
    for (int k = 0; k < 8; ++k) {
        float4 a4 = { p[4 * k + 0] * inv, p[4 * k + 1] * inv,
                      p[4 * k + 2] * inv, p[4 * k + 3] * inv };
        float4 l4 = { (xs[4 * k + 0] - m) - lns, (xs[4 * k + 1] - m) - lns,
                      (xs[4 * k + 2] - m) - lns, (xs[4 * k + 3] - m) - lns };
        ((float4*)oa)[k] = a4;
        ((float4*)ol)[k] = l4;
    }
}

extern "C" void kernel_launch(void* const* d_in, const int* in_sizes, int n_in,
                              void* d_out, int out_size, void* d_ws, size_t ws_size,
                              hipStream_t stream) {
    (void)in_sizes; (void)n_in; (void)out_size; (void)ws_size;
    const float* phi   = (const float*)d_in[0];
    const float* Gamma = (const float*)d_in[1];
    const float* w     = (const float*)d_in[2];
    float* out = (float*)d_out;
    float* wsf = (float*)d_ws;

    k_min<<<256, 256, 0, stream>>>(phi, wsf);
    k_main<<<512, 256, 0, stream>>>(phi, w, Gamma, wsf, out);
}